// Round 2
// baseline (588.848 us; speedup 1.0000x reference)
//
#include <hip/hip_runtime.h>
#include <math.h>

// Problem constants (fixed by setup_inputs): B=8, N=131072, C=76
#define N_PER   131072
#define NBATCH  8
#define REGC    76
#define TOTAL   (NBATCH * N_PER)      // 1,048,576
#define TILE    4096                  // elements per radix block
#define NBLKSEG 32                    // N_PER / TILE
#define BINS    256

// ---------------------------------------------------------------------------
// key transform: float -> uint such that ascending uint sort == descending
// float sort, and stable LSD radix preserves original index order on ties
// (matches stable jnp.argsort(-scores)).
__device__ __forceinline__ unsigned desc_key(float f) {
    unsigned u = __float_as_uint(f);
    // ascending transform: (u>>31) ? ~u : (u | 0x80000000); descending = ~that
    return (u & 0x80000000u) ? u : ~(u | 0x80000000u);
}

// ---------------------------------------------------------------------------
// Stage 1: decode boxes (linear order) + build sort keys/payloads.
__global__ __launch_bounds__(256) void decode_kernel(
    const float* __restrict__ scores, const float* __restrict__ reg,
    const float* __restrict__ xyz, const float* __restrict__ anchor,
    float* __restrict__ boxes8, unsigned* __restrict__ keyA,
    unsigned* __restrict__ payA)
{
    int p = blockIdx.x * 256 + threadIdx.x;           // 0 .. TOTAL-1
    const float* r = reg + (size_t)p * REGC;          // row is 304B, 16B aligned
    const float4* r4 = (const float4*)r;

    float4 q0 = r4[0],  q1 = r4[1],  q2 = r4[2];      // x bins [0:12]
    float4 q3 = r4[3],  q4 = r4[4],  q5 = r4[5];      // z bins [12:24]
    float4 s0 = r4[12], s1 = r4[13], s2 = r4[14], s3 = r4[15]; // [48:64]
    float4 tt = r4[18];                                // [72:76]

    float xa[12] = {q0.x,q0.y,q0.z,q0.w, q1.x,q1.y,q1.z,q1.w, q2.x,q2.y,q2.z,q2.w};
    float za[12] = {q3.x,q3.y,q3.z,q3.w, q4.x,q4.y,q4.z,q4.w, q5.x,q5.y,q5.z,q5.w};
    // ry-bin logits = reg[49..60]: s0.y,s0.z,s0.w | s1.x..w | s2.x..w | s3.x
    float ra[12] = {s0.y,s0.z,s0.w, s1.x,s1.y,s1.z,s1.w, s2.x,s2.y,s2.z,s2.w, s3.x};

    int xb = 0; float xm = xa[0];
#pragma unroll
    for (int c = 1; c < 12; ++c) { if (xa[c] > xm) { xm = xa[c]; xb = c; } }
    int zb = 0; float zm = za[0];
#pragma unroll
    for (int c = 1; c < 12; ++c) { if (za[c] > zm) { zm = za[c]; zb = c; } }
    int yb = 0; float ym = ra[0];
#pragma unroll
    for (int c = 1; c < 12; ++c) { if (ra[c] > ym) { ym = ra[c]; yb = c; } }

    // gathered residuals (rows are L1-resident after the float4 loads)
    float x_res  = r[24 + xb];
    float z_res  = r[36 + zb];
    float ry_res = r[61 + yb];

    float rx = xyz[(size_t)p * 3 + 0];
    float ryy = xyz[(size_t)p * 3 + 1];
    float rz = xyz[(size_t)p * 3 + 2];
    float a0 = anchor[0], a1 = anchor[1], a2 = anchor[2];

    const float APC    = (float)(2.0 * M_PI / 12.0);
    const float HAPC   = (float)(M_PI / 12.0);
    const float TWO_PI = (float)(2.0 * M_PI);
    const float PI_F   = (float)M_PI;

    // heading: replicate jnp.remainder == fmodf then +2pi if negative.
    // __f*_rn to block FMA contraction (mod boundary is a 2*pi discontinuity).
    float vry = __fadd_rn(__fmul_rn((float)yb, APC), __fmul_rn(ry_res, HAPC));
    float m = fmodf(vry, TWO_PI);
    if (m < 0.0f) m += TWO_PI;
    if (m > PI_F) m -= TWO_PI;

    float h = tt.y * a0 + a0;
    float w = tt.z * a1 + a1;
    float l = tt.w * a2 + a2;

    float ox = (((float)xb * 0.5f + 0.25f - 3.0f) + x_res * 0.5f) + rx;
    float oz = (((float)zb * 0.5f + 0.25f - 3.0f) + z_res * 0.5f) + rz;
    float oy = (ryy + s0.x) + h * 0.5f;   // post_process: y + h/2

    float sc = scores[p];

    float4* ob = (float4*)(boxes8 + (size_t)p * 8);
    ob[0] = make_float4(ox, oy, oz, h);
    ob[1] = make_float4(w, l, m, sc);

    keyA[p] = desc_key(sc);
    payA[p] = (unsigned)(p & (N_PER - 1));
}

// ---------------------------------------------------------------------------
// Stage 2a: per-block digit histogram. hist layout: [seg][bin][blk]
__global__ __launch_bounds__(256) void hist_kernel(
    const unsigned* __restrict__ keyIn, unsigned* __restrict__ hist, int shift)
{
    __shared__ unsigned h[BINS];
    int tid = threadIdx.x;
    h[tid] = 0;
    __syncthreads();
    int seg = blockIdx.y, blk = blockIdx.x;
    const unsigned* k = keyIn + (size_t)seg * N_PER + (size_t)blk * TILE;
#pragma unroll
    for (int c = 0; c < TILE / 256; ++c) {
        unsigned d = (k[c * 256 + tid] >> shift) & 255u;
        atomicAdd(&h[d], 1u);
    }
    __syncthreads();
    hist[(size_t)(seg * BINS + tid) * NBLKSEG + blk] = h[tid];
}

// ---------------------------------------------------------------------------
// Stage 2b: per-segment scan. In-place: hist[seg][bin][blk] becomes the
// global (within-segment) exclusive offset for (bin, blk).
__global__ __launch_bounds__(256) void scan_kernel(unsigned* __restrict__ hist)
{
    int seg = blockIdx.x, bin = threadIdx.x;
    unsigned* hp = hist + (size_t)(seg * BINS + bin) * NBLKSEG;
    unsigned run = 0;
#pragma unroll
    for (int blk = 0; blk < NBLKSEG; ++blk) {
        unsigned c = hp[blk];
        hp[blk] = run;
        run += c;
    }
    __shared__ unsigned sc[BINS];
    sc[bin] = run;
    __syncthreads();
    // Hillis-Steele inclusive scan over bins
    for (int off = 1; off < BINS; off <<= 1) {
        unsigned v = (bin >= off) ? sc[bin - off] : 0u;
        __syncthreads();
        sc[bin] += v;
        __syncthreads();
    }
    unsigned excl = sc[bin] - run;   // exclusive prefix of bin totals
#pragma unroll
    for (int blk = 0; blk < NBLKSEG; ++blk) hp[blk] += excl;
}

// ---------------------------------------------------------------------------
// Stage 2c: stable scatter. Block-stable rank via per-wave ballot matching.
__global__ __launch_bounds__(256) void scatter_kernel(
    const unsigned* __restrict__ keyIn, const unsigned* __restrict__ payIn,
    unsigned* __restrict__ keyOut, unsigned* __restrict__ payOut,
    const unsigned* __restrict__ hist, int shift)
{
    __shared__ unsigned offs[BINS];
    __shared__ unsigned running[BINS];
    __shared__ unsigned whist[4][BINS];
    int tid = threadIdx.x;
    int seg = blockIdx.y, blk = blockIdx.x;
    int wave = tid >> 6, lane = tid & 63;
    unsigned long long lmask = (1ull << lane) - 1ull;

    offs[tid] = hist[(size_t)(seg * BINS + tid) * NBLKSEG + blk];
    running[tid] = 0;
#pragma unroll
    for (int w2 = 0; w2 < 4; ++w2) whist[w2][tid] = 0;

    const unsigned* ki = keyIn + (size_t)seg * N_PER + (size_t)blk * TILE;
    const unsigned* pi = payIn + (size_t)seg * N_PER + (size_t)blk * TILE;
    unsigned* ko = keyOut + (size_t)seg * N_PER;
    unsigned* po = payOut + (size_t)seg * N_PER;

    for (int c = 0; c < TILE / 256; ++c) {
        __syncthreads();   // whist zeroed + running updated from prev chunk
        unsigned key = ki[c * 256 + tid];
        unsigned pay = pi[c * 256 + tid];
        unsigned d = (key >> shift) & 255u;
        // wave-level same-digit peer mask via 8 ballots
        unsigned long long peers = ~0ull;
#pragma unroll
        for (int b = 0; b < 8; ++b) {
            unsigned long long vote = __ballot((d >> b) & 1u);
            peers &= ((d >> b) & 1u) ? vote : ~vote;
        }
        unsigned rank = (unsigned)__popcll(peers & lmask);
        unsigned cnt  = (unsigned)__popcll(peers);
        if (rank == 0) whist[wave][d] = cnt;   // unique (wave,digit) writer
        __syncthreads();
        unsigned prefix = running[d];
#pragma unroll
        for (int w2 = 0; w2 < 4; ++w2) { if (w2 < wave) prefix += whist[w2][d]; }
        unsigned pos = offs[d] + prefix + rank;
        ko[pos] = key;
        po[pos] = pay;
        __syncthreads();   // all reads of running/whist done
        unsigned sum = whist[0][tid] + whist[1][tid] + whist[2][tid] + whist[3][tid];
        running[tid] += sum;
        whist[0][tid] = 0; whist[1][tid] = 0; whist[2][tid] = 0; whist[3][tid] = 0;
    }
}

// ---------------------------------------------------------------------------
// Stage 3: gather boxes in sorted order. 2 threads per 32B row (float4 each).
__global__ __launch_bounds__(256) void gather_kernel(
    const float* __restrict__ boxes8, const unsigned* __restrict__ pay,
    float* __restrict__ out)
{
    int g = blockIdx.x * 256 + threadIdx.x;   // 2 * TOTAL threads
    int row = g >> 1, half = g & 1;
    int b = row >> 17;                        // N_PER = 2^17
    unsigned i = pay[row];
    const float4* src = (const float4*)(boxes8 + ((size_t)((b << 17) | (int)i)) * 8);
    float4 v = src[half];
    ((float4*)(out + (size_t)row * 8))[half] = v;
}

// ---------------------------------------------------------------------------
extern "C" void kernel_launch(void* const* d_in, const int* in_sizes, int n_in,
                              void* d_out, int out_size, void* d_ws, size_t ws_size,
                              hipStream_t stream)
{
    const float* scores = (const float*)d_in[0];
    const float* reg    = (const float*)d_in[1];
    const float* xyz    = (const float*)d_in[2];
    const float* anchor = (const float*)d_in[3];
    float* out = (float*)d_out;

    // workspace carve-up: needs 50,593,792 bytes
    char* ws = (char*)d_ws;
    float*    boxes8 = (float*)ws;
    size_t    off    = (size_t)TOTAL * 8 * sizeof(float);          // 33.55 MB
    unsigned* keyA = (unsigned*)(ws + off); off += (size_t)TOTAL * 4;
    unsigned* payA = (unsigned*)(ws + off); off += (size_t)TOTAL * 4;
    unsigned* keyB = (unsigned*)(ws + off); off += (size_t)TOTAL * 4;
    unsigned* payB = (unsigned*)(ws + off); off += (size_t)TOTAL * 4;
    unsigned* hist = (unsigned*)(ws + off); off += (size_t)NBATCH * BINS * NBLKSEG * 4;
    (void)ws_size; (void)in_sizes; (void)n_in; (void)out_size;

    decode_kernel<<<TOTAL / 256, 256, 0, stream>>>(scores, reg, xyz, anchor,
                                                   boxes8, keyA, payA);

    unsigned *ka = keyA, *pa = payA, *kb = keyB, *pb = payB;
    for (int pass = 0; pass < 4; ++pass) {
        int shift = pass * 8;
        hist_kernel<<<dim3(NBLKSEG, NBATCH), 256, 0, stream>>>(ka, hist, shift);
        scan_kernel<<<NBATCH, 256, 0, stream>>>(hist);
        scatter_kernel<<<dim3(NBLKSEG, NBATCH), 256, 0, stream>>>(ka, pa, kb, pb,
                                                                  hist, shift);
        unsigned* t;
        t = ka; ka = kb; kb = t;
        t = pa; pa = pb; pb = t;
    }
    // after 4 passes, sorted keys/payloads are back in keyA/payA (== ka/pa)

    gather_kernel<<<(TOTAL * 2) / 256, 256, 0, stream>>>(boxes8, pa, out);
}